// Round 14
// baseline (98.038 us; speedup 1.0000x reference)
//
#include <hip/hip_runtime.h>
#include <hip/hip_bf16.h>

// ParameterMixture = thin GEMM C[32 x 1M] = P[32x64] @ W[64 x 1M], MFMA bf16
// split-compensated (Ph*Wh + Ph*Wl + Pl*Wh), layouts verified R6-R13.
//
// R14: ROWS-OUTER traversal (translation-pressure fix). All prior variants
// cycle through all 64 expert rows (4MB apart) within every column quantum
// -> ~96 live 2MB pages per CU >> utlb, stalling every access regardless of
// L3/HBM source (matches R10: L3-pass == HBM-pass, pipes idle). This round:
// each wave owns 128 cols; rowgroup loop OUTERMOST (16 rows per phase, 4
// phases), acc[4 tiles][16] (64 VGPR) lives across phases, one store burst
// at the end. Per-wave live row-set: 16 (was 64). GRID=2048, depth-2
// prefetch across rowgroups, nt loads/stores.

typedef __attribute__((ext_vector_type(8)))  short short8v;
typedef __attribute__((ext_vector_type(16))) float f32x16;
typedef __attribute__((ext_vector_type(4)))  float float4v;

constexpr int E = 64;
constexpr int K = 8;
constexpr int B = 32;
constexpr int OUT_DIM = 1024;

constexpr int NCOL     = 1024 * 1024;         // W cols
constexpr int BLK      = 256;
constexpr int CPW      = 128;                 // cols per wave (4 MFMA tiles)
constexpr int GRID     = NCOL / CPW / 4;      // 2048 blocks (4 waves each)
constexpr int WM_ELEMS = B * NCOL;
constexpr int OB4      = OUT_DIM / 4;         // 256

struct HL { short h; short l; };

__device__ __forceinline__ HL split_bf16(float x) {
    const __hip_bfloat16 hb = __float2bfloat16(x);
    const float          hf = __bfloat162float(hb);
    const __hip_bfloat16 lb = __float2bfloat16(x - hf);
    HL r;
    r.h = __builtin_bit_cast(short, hb);
    r.l = __builtin_bit_cast(short, lb);
    return r;
}

__global__ __launch_bounds__(BLK, 2) void ParameterMixture_86835648790543_kernel(
    const float* __restrict__ wprobs,   // [B,K]
    const float* __restrict__ bprobs,   // [B,K]
    const int*   __restrict__ widx,     // [B,K]
    const int*   __restrict__ bidx,     // [B,K]
    const float* __restrict__ wbank,    // [E, NCOL]
    const float* __restrict__ bbank,    // [E,O]
    float*       __restrict__ out)      // [B*NCOL] ++ [B*O]
{
    const int bid  = blockIdx.x;
    const int t    = threadIdx.x;
    const int wv   = t >> 6;
    const int lane = t & 63;
    const int m    = lane & 31;         // A row (batch)
    const int kh   = (lane >> 5) * 8;   // k half-offset
    const int cl   = lane & 31;         // column-group index

    // ---- bias prologue on blocks 0..31 (tiny, fp32 exact) ----
    if (bid < 32) {
        const int tt   = bid * BLK + t;
        const int b    = tt / OB4;
        const int off4 = tt % OB4;
        const float4* __restrict__ bb4 = (const float4*)bbank;
        float4 a4 = make_float4(0.f, 0.f, 0.f, 0.f);
#pragma unroll
        for (int k = 0; k < K; ++k) {
            const float p = bprobs[b * K + k];
            const int   e = bidx[b * K + k];
            const float4 v = bb4[e * OB4 + off4];
            a4.x += p * v.x; a4.y += p * v.y;
            a4.z += p * v.z; a4.w += p * v.w;
        }
        ((float4*)(out + WM_ELEMS))[tt] = a4;
    }

    // ---- per-lane A-fragments (P in bf16 hi/lo, MFMA layout) ----
    float wp[K];
    int   wi[K];
#pragma unroll
    for (int k2 = 0; k2 < K; ++k2) {
        wp[k2] = wprobs[m * K + k2];
        wi[k2] = widx[m * K + k2];
    }
    short8v aH[4], aL[4];
#pragma unroll
    for (int s = 0; s < 4; ++s) {
#pragma unroll
        for (int j = 0; j < 8; ++j) {
            const int e = s * 16 + kh + j;
            float p = 0.f;
#pragma unroll
            for (int k2 = 0; k2 < K; ++k2)
                p += (wi[k2] == e) ? wp[k2] : 0.f;
            const HL r = split_bf16(p);
            aH[s][j] = r.h;
            aL[s][j] = r.l;
        }
    }

    const size_t ncol     = (size_t)NCOL;
    const int    wave_id  = bid * 4 + wv;
    const int    col_base = wave_id * CPW;

    // fixed per-lane column pointer; only the row advances (rows-outer)
    const float* __restrict__ wbase = wbank + col_base + 4 * cl;

    // load rowgroup rg: rows rg*16 + kh + j (j=0..7), 8 nt dwordx4 loads
    auto load_rg = [&](float4v (&w)[8], int rg) {
        const int r0 = rg * 16 + kh;
#pragma unroll
        for (int j = 0; j < 8; ++j)
            w[j] = __builtin_nontemporal_load(
                (const float4v*)(wbase + (size_t)(r0 + j) * ncol));
    };

    // accumulators for the wave's full 128-col output: 4 tiles x 16 regs
    f32x16 acc[4];
#pragma unroll
    for (int tt2 = 0; tt2 < 4; ++tt2)
#pragma unroll
        for (int i = 0; i < 16; ++i) acc[tt2][i] = 0.f;

    // one rowgroup: cvt 32 floats -> 4 tiles' bh/bl, then 12 MFMA
    auto compute_rg = [&](const float4v (&w)[8], int rg) {
        short8v bh[4], bl[4];
#pragma unroll
        for (int j = 0; j < 8; ++j) {
            const HL rx = split_bf16(w[j][0]);
            const HL ry = split_bf16(w[j][1]);
            const HL rz = split_bf16(w[j][2]);
            const HL rw = split_bf16(w[j][3]);
            bh[0][j] = rx.h; bl[0][j] = rx.l;
            bh[1][j] = ry.h; bl[1][j] = ry.l;
            bh[2][j] = rz.h; bl[2][j] = rz.l;
            bh[3][j] = rw.h; bl[3][j] = rw.l;
        }
#pragma unroll
        for (int tt2 = 0; tt2 < 4; ++tt2) {
            acc[tt2] = __builtin_amdgcn_mfma_f32_32x32x16_bf16(aH[rg], bh[tt2], acc[tt2], 0, 0, 0);
            acc[tt2] = __builtin_amdgcn_mfma_f32_32x32x16_bf16(aH[rg], bl[tt2], acc[tt2], 0, 0, 0);
            acc[tt2] = __builtin_amdgcn_mfma_f32_32x32x16_bf16(aL[rg], bh[tt2], acc[tt2], 0, 0, 0);
        }
    };

    // rows-outer sweep: 16-row phases, depth-2 prefetch, fully static
    float4v bufA[8], bufB[8];
    load_rg(bufA, 0);
    load_rg(bufB, 1);
    compute_rg(bufA, 0);  load_rg(bufA, 2);
    compute_rg(bufB, 1);  load_rg(bufB, 3);
    compute_rg(bufA, 2);
    compute_rg(bufB, 3);

    // single store burst: lane cl holds cols col_base+4cl..+3 of each C row
    float* __restrict__ ob = out + col_base + 4 * cl + (size_t)((lane >> 5) * 4) * ncol;
#pragma unroll
    for (int reg = 0; reg < 16; ++reg) {
        const int row = (reg & 3) + 8 * (reg >> 2);
        float4v v;
        v[0] = acc[0][reg]; v[1] = acc[1][reg];
        v[2] = acc[2][reg]; v[3] = acc[3][reg];
        __builtin_nontemporal_store(v, (float4v*)(ob + (size_t)row * ncol));
    }
}

extern "C" void kernel_launch(void* const* d_in, const int* in_sizes, int n_in,
                              void* d_out, int out_size, void* d_ws, size_t ws_size,
                              hipStream_t stream) {
    const float* wprobs = (const float*)d_in[0];
    const float* bprobs = (const float*)d_in[1];
    const int*   widx   = (const int*)d_in[2];
    const int*   bidx   = (const int*)d_in[3];
    const float* wbank  = (const float*)d_in[4];
    const float* bbank  = (const float*)d_in[5];
    float*       out    = (float*)d_out;

    ParameterMixture_86835648790543_kernel<<<GRID, BLK, 0, stream>>>(
        wprobs, bprobs, widx, bidx, wbank, bbank, out);
}

// Round 15
// 86.499 us; speedup vs baseline: 1.1334x; 1.1334x over previous
//
#include <hip/hip_runtime.h>
#include <hip/hip_bf16.h>

// ParameterMixture = thin GEMM C[32 x 1M] = P[32x64] @ W[64 x 1M], MFMA bf16
// split-compensated (Ph*Wh + Ph*Wl + Pl*Wh), layouts verified R6-R14.
//
// R15 = R13 (best: 90.7us; depth-4 rowgroup pipeline, nt loads/stores,
// GRID=512 -> 8 waves/CU) with the prefetch PEELED: R13's tail clamp issued
// 32 wasted VMEM loads per wave (25% extra load instrs, all bunched in the
// final step). Steps 0-2 prefetch; step 3 is compute+store only.

typedef __attribute__((ext_vector_type(8)))  short short8v;
typedef __attribute__((ext_vector_type(16))) float f32x16;
typedef __attribute__((ext_vector_type(4)))  float float4v;

constexpr int E = 64;
constexpr int K = 8;
constexpr int B = 32;
constexpr int OUT_DIM = 1024;

constexpr int NCOL     = 1024 * 1024;         // W cols
constexpr int BLK      = 256;
constexpr int GRID     = 512;                 // 2 blocks/CU, 8 waves/CU
constexpr int WAVES    = GRID * 4;            // 2048
constexpr int CPW      = NCOL / WAVES;        // 512 cols per wave
constexpr int CSTEP    = 128;                 // cols per step (4 tiles x 32)
constexpr int STEPS    = CPW / CSTEP;         // 4
constexpr int WM_ELEMS = B * NCOL;
constexpr int OB4      = OUT_DIM / 4;         // 256

struct HL { short h; short l; };

__device__ __forceinline__ HL split_bf16(float x) {
    const __hip_bfloat16 hb = __float2bfloat16(x);
    const float          hf = __bfloat162float(hb);
    const __hip_bfloat16 lb = __float2bfloat16(x - hf);
    HL r;
    r.h = __builtin_bit_cast(short, hb);
    r.l = __builtin_bit_cast(short, lb);
    return r;
}

__global__ __launch_bounds__(BLK, 2) void ParameterMixture_86835648790543_kernel(
    const float* __restrict__ wprobs,   // [B,K]
    const float* __restrict__ bprobs,   // [B,K]
    const int*   __restrict__ widx,     // [B,K]
    const int*   __restrict__ bidx,     // [B,K]
    const float* __restrict__ wbank,    // [E, NCOL]
    const float* __restrict__ bbank,    // [E,O]
    float*       __restrict__ out)      // [B*NCOL] ++ [B*O]
{
    const int bid  = blockIdx.x;
    const int t    = threadIdx.x;
    const int wv   = t >> 6;
    const int lane = t & 63;
    const int m    = lane & 31;         // A row (batch)
    const int kh   = (lane >> 5) * 8;   // k half-offset
    const int cl   = lane & 31;         // column-group index

    // ---- bias prologue on blocks 0..31 (tiny, fp32 exact) ----
    if (bid < 32) {
        const int tt   = bid * BLK + t;
        const int b    = tt / OB4;
        const int off4 = tt % OB4;
        const float4* __restrict__ bb4 = (const float4*)bbank;
        float4 a4 = make_float4(0.f, 0.f, 0.f, 0.f);
#pragma unroll
        for (int k = 0; k < K; ++k) {
            const float p = bprobs[b * K + k];
            const int   e = bidx[b * K + k];
            const float4 v = bb4[e * OB4 + off4];
            a4.x += p * v.x; a4.y += p * v.y;
            a4.z += p * v.z; a4.w += p * v.w;
        }
        ((float4*)(out + WM_ELEMS))[tt] = a4;
    }

    // ---- per-lane A-fragments (P in bf16 hi/lo, MFMA layout) ----
    float wp[K];
    int   wi[K];
#pragma unroll
    for (int k2 = 0; k2 < K; ++k2) {
        wp[k2] = wprobs[m * K + k2];
        wi[k2] = widx[m * K + k2];
    }
    short8v aH[4], aL[4];
#pragma unroll
    for (int s = 0; s < 4; ++s) {
#pragma unroll
        for (int j = 0; j < 8; ++j) {
            const int e = s * 16 + kh + j;
            float p = 0.f;
#pragma unroll
            for (int k2 = 0; k2 < K; ++k2)
                p += (wi[k2] == e) ? wp[k2] : 0.f;
            const HL r = split_bf16(p);
            aH[s][j] = r.h;
            aL[s][j] = r.l;
        }
    }

    const size_t ncol     = (size_t)NCOL;
    const int    wave_id  = bid * 4 + wv;
    const int    col_base = wave_id * CPW;

    // rowgroup g: step = g>>2, rows (g&3)*16 + kh + j, 8 nt dwordx4 loads
    auto load_rg = [&](float4v (&w)[8], int g) {
        const int c0 = col_base + (g >> 2) * CSTEP + 4 * cl;
        const int r0 = (g & 3) * 16 + kh;
        const float* __restrict__ base = wbank + c0;
#pragma unroll
        for (int j = 0; j < 8; ++j)
            w[j] = __builtin_nontemporal_load(
                (const float4v*)(base + (size_t)(r0 + j) * ncol));
    };

    float4v bufA[8], bufB[8], bufC[8], bufD[8];
    load_rg(bufA, 0);
    load_rg(bufB, 1);
    load_rg(bufC, 2);
    load_rg(bufD, 3);

    f32x16 acc[4];

    // one rowgroup: cvt 32 floats -> 4 tiles' bh/bl, then 12 MFMA
    auto compute_rg = [&](const float4v (&w)[8], int rg) {
        short8v bh[4], bl[4];
#pragma unroll
        for (int j = 0; j < 8; ++j) {
            const HL rx = split_bf16(w[j][0]);
            const HL ry = split_bf16(w[j][1]);
            const HL rz = split_bf16(w[j][2]);
            const HL rw = split_bf16(w[j][3]);
            bh[0][j] = rx.h; bl[0][j] = rx.l;
            bh[1][j] = ry.h; bl[1][j] = ry.l;
            bh[2][j] = rz.h; bl[2][j] = rz.l;
            bh[3][j] = rw.h; bl[3][j] = rw.l;
        }
#pragma unroll
        for (int tt2 = 0; tt2 < 4; ++tt2) {
            acc[tt2] = __builtin_amdgcn_mfma_f32_32x32x16_bf16(aH[rg], bh[tt2], acc[tt2], 0, 0, 0);
            acc[tt2] = __builtin_amdgcn_mfma_f32_32x32x16_bf16(aH[rg], bl[tt2], acc[tt2], 0, 0, 0);
            acc[tt2] = __builtin_amdgcn_mfma_f32_32x32x16_bf16(aL[rg], bh[tt2], acc[tt2], 0, 0, 0);
        }
    };

    auto store_step = [&](int step) {
        const int c0 = col_base + step * CSTEP + 4 * cl;
        float* __restrict__ ob = out + c0 + (size_t)((lane >> 5) * 4) * ncol;
#pragma unroll
        for (int reg = 0; reg < 16; ++reg) {
            const int row = (reg & 3) + 8 * (reg >> 2);
            float4v v;
            v[0] = acc[0][reg]; v[1] = acc[1][reg];
            v[2] = acc[2][reg]; v[3] = acc[3][reg];
            __builtin_nontemporal_store(v, (float4v*)(ob + (size_t)row * ncol));
        }
    };

    // steps 0..2: compute + depth-4 prefetch of the next step's rowgroups
#pragma unroll 1
    for (int step = 0; step < STEPS - 1; ++step) {
#pragma unroll
        for (int tt2 = 0; tt2 < 4; ++tt2)
#pragma unroll
            for (int i = 0; i < 16; ++i) acc[tt2][i] = 0.f;

        const int g0 = step * 4;
        compute_rg(bufA, 0);  load_rg(bufA, g0 + 4);
        compute_rg(bufB, 1);  load_rg(bufB, g0 + 5);
        compute_rg(bufC, 2);  load_rg(bufC, g0 + 6);
        compute_rg(bufD, 3);  load_rg(bufD, g0 + 7);

        store_step(step);
    }

    // step 3 (peeled): compute + store only, no wasted prefetch
    {
#pragma unroll
        for (int tt2 = 0; tt2 < 4; ++tt2)
#pragma unroll
            for (int i = 0; i < 16; ++i) acc[tt2][i] = 0.f;

        compute_rg(bufA, 0);
        compute_rg(bufB, 1);
        compute_rg(bufC, 2);
        compute_rg(bufD, 3);

        store_step(STEPS - 1);
    }
}

extern "C" void kernel_launch(void* const* d_in, const int* in_sizes, int n_in,
                              void* d_out, int out_size, void* d_ws, size_t ws_size,
                              hipStream_t stream) {
    const float* wprobs = (const float*)d_in[0];
    const float* bprobs = (const float*)d_in[1];
    const int*   widx   = (const int*)d_in[2];
    const int*   bidx   = (const int*)d_in[3];
    const float* wbank  = (const float*)d_in[4];
    const float* bbank  = (const float*)d_in[5];
    float*       out    = (float*)d_out;

    ParameterMixture_86835648790543_kernel<<<GRID, BLK, 0, stream>>>(
        wprobs, bprobs, widx, bidx, wbank, bbank, out);
}

// Round 18
// 85.960 us; speedup vs baseline: 1.1405x; 1.0063x over previous
//
#include <hip/hip_runtime.h>
#include <hip/hip_bf16.h>

// ParameterMixture = thin GEMM C[32 x 1M] = P[32x64] @ W[64 x 1M], MFMA bf16
// split-compensated (Ph*Wh + Ph*Wl + Pl*Wh), layouts verified R6-R15.
//
// FINAL (= R15, verified 86.5us / absmax 9.8e-4): depth-4 rowgroup pipeline,
// nt loads/stores, GRID=512 (2 blocks/CU, 8 waves/CU), prefetch peeled in
// the last step. 388 MB irreducible fp32 traffic @ ~4.5 TB/s effective
// (71% of copy ceiling); all issue pipes <11%. Pattern-shaping axes (R7,
// R12, R14, R16/17) all null/negative -> structural floor for this shape.

typedef __attribute__((ext_vector_type(8)))  short short8v;
typedef __attribute__((ext_vector_type(16))) float f32x16;
typedef __attribute__((ext_vector_type(4)))  float float4v;

constexpr int E = 64;
constexpr int K = 8;
constexpr int B = 32;
constexpr int OUT_DIM = 1024;

constexpr int NCOL     = 1024 * 1024;         // W cols
constexpr int BLK      = 256;
constexpr int GRID     = 512;                 // 2 blocks/CU, 8 waves/CU
constexpr int WAVES    = GRID * 4;            // 2048
constexpr int CPW      = NCOL / WAVES;        // 512 cols per wave
constexpr int CSTEP    = 128;                 // cols per step (4 tiles x 32)
constexpr int STEPS    = CPW / CSTEP;         // 4
constexpr int WM_ELEMS = B * NCOL;
constexpr int OB4      = OUT_DIM / 4;         // 256

struct HL { short h; short l; };

__device__ __forceinline__ HL split_bf16(float x) {
    const __hip_bfloat16 hb = __float2bfloat16(x);
    const float          hf = __bfloat162float(hb);
    const __hip_bfloat16 lb = __float2bfloat16(x - hf);
    HL r;
    r.h = __builtin_bit_cast(short, hb);
    r.l = __builtin_bit_cast(short, lb);
    return r;
}

__global__ __launch_bounds__(BLK, 2) void ParameterMixture_86835648790543_kernel(
    const float* __restrict__ wprobs,   // [B,K]
    const float* __restrict__ bprobs,   // [B,K]
    const int*   __restrict__ widx,     // [B,K]
    const int*   __restrict__ bidx,     // [B,K]
    const float* __restrict__ wbank,    // [E, NCOL]
    const float* __restrict__ bbank,    // [E,O]
    float*       __restrict__ out)      // [B*NCOL] ++ [B*O]
{
    const int bid  = blockIdx.x;
    const int t    = threadIdx.x;
    const int wv   = t >> 6;
    const int lane = t & 63;
    const int m    = lane & 31;         // A row (batch)
    const int kh   = (lane >> 5) * 8;   // k half-offset
    const int cl   = lane & 31;         // column-group index

    // ---- bias prologue on blocks 0..31 (tiny, fp32 exact) ----
    if (bid < 32) {
        const int tt   = bid * BLK + t;
        const int b    = tt / OB4;
        const int off4 = tt % OB4;
        const float4* __restrict__ bb4 = (const float4*)bbank;
        float4 a4 = make_float4(0.f, 0.f, 0.f, 0.f);
#pragma unroll
        for (int k = 0; k < K; ++k) {
            const float p = bprobs[b * K + k];
            const int   e = bidx[b * K + k];
            const float4 v = bb4[e * OB4 + off4];
            a4.x += p * v.x; a4.y += p * v.y;
            a4.z += p * v.z; a4.w += p * v.w;
        }
        ((float4*)(out + WM_ELEMS))[tt] = a4;
    }

    // ---- per-lane A-fragments (P in bf16 hi/lo, MFMA layout) ----
    float wp[K];
    int   wi[K];
#pragma unroll
    for (int k2 = 0; k2 < K; ++k2) {
        wp[k2] = wprobs[m * K + k2];
        wi[k2] = widx[m * K + k2];
    }
    short8v aH[4], aL[4];
#pragma unroll
    for (int s = 0; s < 4; ++s) {
#pragma unroll
        for (int j = 0; j < 8; ++j) {
            const int e = s * 16 + kh + j;
            float p = 0.f;
#pragma unroll
            for (int k2 = 0; k2 < K; ++k2)
                p += (wi[k2] == e) ? wp[k2] : 0.f;
            const HL r = split_bf16(p);
            aH[s][j] = r.h;
            aL[s][j] = r.l;
        }
    }

    const size_t ncol     = (size_t)NCOL;
    const int    wave_id  = bid * 4 + wv;
    const int    col_base = wave_id * CPW;

    // rowgroup g: step = g>>2, rows (g&3)*16 + kh + j, 8 nt dwordx4 loads
    auto load_rg = [&](float4v (&w)[8], int g) {
        const int c0 = col_base + (g >> 2) * CSTEP + 4 * cl;
        const int r0 = (g & 3) * 16 + kh;
        const float* __restrict__ base = wbank + c0;
#pragma unroll
        for (int j = 0; j < 8; ++j)
            w[j] = __builtin_nontemporal_load(
                (const float4v*)(base + (size_t)(r0 + j) * ncol));
    };

    float4v bufA[8], bufB[8], bufC[8], bufD[8];
    load_rg(bufA, 0);
    load_rg(bufB, 1);
    load_rg(bufC, 2);
    load_rg(bufD, 3);

    f32x16 acc[4];

    // one rowgroup: cvt 32 floats -> 4 tiles' bh/bl, then 12 MFMA
    auto compute_rg = [&](const float4v (&w)[8], int rg) {
        short8v bh[4], bl[4];
#pragma unroll
        for (int j = 0; j < 8; ++j) {
            const HL rx = split_bf16(w[j][0]);
            const HL ry = split_bf16(w[j][1]);
            const HL rz = split_bf16(w[j][2]);
            const HL rw = split_bf16(w[j][3]);
            bh[0][j] = rx.h; bl[0][j] = rx.l;
            bh[1][j] = ry.h; bl[1][j] = ry.l;
            bh[2][j] = rz.h; bl[2][j] = rz.l;
            bh[3][j] = rw.h; bl[3][j] = rw.l;
        }
#pragma unroll
        for (int tt2 = 0; tt2 < 4; ++tt2) {
            acc[tt2] = __builtin_amdgcn_mfma_f32_32x32x16_bf16(aH[rg], bh[tt2], acc[tt2], 0, 0, 0);
            acc[tt2] = __builtin_amdgcn_mfma_f32_32x32x16_bf16(aH[rg], bl[tt2], acc[tt2], 0, 0, 0);
            acc[tt2] = __builtin_amdgcn_mfma_f32_32x32x16_bf16(aL[rg], bh[tt2], acc[tt2], 0, 0, 0);
        }
    };

    auto store_step = [&](int step) {
        const int c0 = col_base + step * CSTEP + 4 * cl;
        float* __restrict__ ob = out + c0 + (size_t)((lane >> 5) * 4) * ncol;
#pragma unroll
        for (int reg = 0; reg < 16; ++reg) {
            const int row = (reg & 3) + 8 * (reg >> 2);
            float4v v;
            v[0] = acc[0][reg]; v[1] = acc[1][reg];
            v[2] = acc[2][reg]; v[3] = acc[3][reg];
            __builtin_nontemporal_store(v, (float4v*)(ob + (size_t)row * ncol));
        }
    };

    // steps 0..2: compute + depth-4 prefetch of the next step's rowgroups
#pragma unroll 1
    for (int step = 0; step < STEPS - 1; ++step) {
#pragma unroll
        for (int tt2 = 0; tt2 < 4; ++tt2)
#pragma unroll
            for (int i = 0; i < 16; ++i) acc[tt2][i] = 0.f;

        const int g0 = step * 4;
        compute_rg(bufA, 0);  load_rg(bufA, g0 + 4);
        compute_rg(bufB, 1);  load_rg(bufB, g0 + 5);
        compute_rg(bufC, 2);  load_rg(bufC, g0 + 6);
        compute_rg(bufD, 3);  load_rg(bufD, g0 + 7);

        store_step(step);
    }

    // step 3 (peeled): compute + store only, no wasted prefetch
    {
#pragma unroll
        for (int tt2 = 0; tt2 < 4; ++tt2)
#pragma unroll
            for (int i = 0; i < 16; ++i) acc[tt2][i] = 0.f;

        compute_rg(bufA, 0);
        compute_rg(bufB, 1);
        compute_rg(bufC, 2);
        compute_rg(bufD, 3);

        store_step(STEPS - 1);
    }
}

extern "C" void kernel_launch(void* const* d_in, const int* in_sizes, int n_in,
                              void* d_out, int out_size, void* d_ws, size_t ws_size,
                              hipStream_t stream) {
    const float* wprobs = (const float*)d_in[0];
    const float* bprobs = (const float*)d_in[1];
    const int*   widx   = (const int*)d_in[2];
    const int*   bidx   = (const int*)d_in[3];
    const float* wbank  = (const float*)d_in[4];
    const float* bbank  = (const float*)d_in[5];
    float*       out    = (float*)d_out;

    ParameterMixture_86835648790543_kernel<<<GRID, BLK, 0, stream>>>(
        wprobs, bprobs, widx, bidx, wbank, bbank, out);
}